// Round 1
// baseline (1332.372 us; speedup 1.0000x reference)
//
#include <hip/hip_runtime.h>
#include <hip/hip_bf16.h>

#define H 1024
#define F 4096
#define NE 8
#define T 4096
#define BM 64

typedef unsigned short u16;
typedef float floatx4 __attribute__((ext_vector_type(4)));
typedef short short8 __attribute__((ext_vector_type(8)));

__device__ __forceinline__ u16 f2bf(float f) {
  union { float f; unsigned int u; } c; c.f = f;
  unsigned int u = c.u;
  return (u16)((u + 0x7fffu + ((u >> 16) & 1u)) >> 16);
}

// ---------------- router: one wave per token, fp64 logits ----------------
__global__ __launch_bounds__(256) void router_kernel(
    const float* __restrict__ x, const float* __restrict__ Wr,
    int* __restrict__ cnt, int* __restrict__ tok, float* __restrict__ wgt) {
  int t = (blockIdx.x * 256 + threadIdx.x) >> 6;  // token id, 0..4095
  int lane = threadIdx.x & 63;
  const float* xr = x + (size_t)t * H;
  double p[NE];
#pragma unroll
  for (int e = 0; e < NE; ++e) p[e] = 0.0;
  for (int k = lane; k < H; k += 64) {
    float xv = xr[k];
    const float4* wr4 = reinterpret_cast<const float4*>(Wr + k * NE);
    float4 a = wr4[0], b = wr4[1];
    p[0] += (double)xv * a.x; p[1] += (double)xv * a.y;
    p[2] += (double)xv * a.z; p[3] += (double)xv * a.w;
    p[4] += (double)xv * b.x; p[5] += (double)xv * b.y;
    p[6] += (double)xv * b.z; p[7] += (double)xv * b.w;
  }
#pragma unroll
  for (int e = 0; e < NE; ++e) {
#pragma unroll
    for (int off = 32; off; off >>= 1) p[e] += __shfl_down(p[e], off, 64);
  }
  if (lane == 0) {
    int i0 = 0;
#pragma unroll
    for (int e = 1; e < NE; ++e) if (p[e] > p[i0]) i0 = e;
    int i1 = (i0 == 0) ? 1 : 0;
#pragma unroll
    for (int e = 0; e < NE; ++e) if (e != i0 && p[e] > p[i1]) i1 = e;
    double d = exp(p[i1] - p[i0]);           // <= 1
    float w0 = (float)(1.0 / (1.0 + d));
    float w1 = (float)(d / (1.0 + d));
    int pos0 = atomicAdd(&cnt[i0], 1);
    tok[i0 * T + pos0] = t; wgt[i0 * T + pos0] = w0;
    int pos1 = atomicAdd(&cnt[i1], 1);
    tok[i1 * T + pos1] = t; wgt[i1 * T + pos1] = w1;
  }
}

// ---------------- x -> bf16 ----------------
__global__ __launch_bounds__(256) void convert_x_kernel(
    const float* __restrict__ x, u16* __restrict__ xb) {
  int i = blockIdx.x * 256 + threadIdx.x;
  float4 v = reinterpret_cast<const float4*>(x)[i];
  ushort4 o;
  o.x = f2bf(v.x); o.y = f2bf(v.y); o.z = f2bf(v.z); o.w = f2bf(v.w);
  reinterpret_cast<ushort4*>(xb)[i] = o;
}

// ---------------- [E][R][C] f32 -> [E][C][R] bf16 tiled transpose ----------------
__global__ __launch_bounds__(256) void transpose_bf16_kernel(
    const float* __restrict__ src, u16* __restrict__ dst, int R, int C) {
  __shared__ float tile[32][33];
  int e = blockIdx.z;
  int r0 = blockIdx.y << 5, c0 = blockIdx.x << 5;
  const float* s = src + (size_t)e * R * C;
  u16* d = dst + (size_t)e * R * C;
  int tx = threadIdx.x, ty = threadIdx.y;  // 32 x 8
#pragma unroll
  for (int i = 0; i < 4; ++i)
    tile[ty + i * 8][tx] = s[(size_t)(r0 + ty + i * 8) * C + c0 + tx];
  __syncthreads();
#pragma unroll
  for (int i = 0; i < 4; ++i)
    d[(size_t)(c0 + ty + i * 8) * R + r0 + tx] = f2bf(tile[tx][ty + i * 8]);
}

// ---------------- fused grouped FFN ----------------
// block: (token-tile, expert, ffn-half). 512 thr = 8 waves.
// out[64,1024] per block; FFN chunked by 64: Hc = gelu(X@W1+b1) -> LDS,
// out += Hc @ W2. Split-K over ffn-half via atomicAdd.
__global__ __launch_bounds__(512) void moe_ffn_kernel(
    const u16* __restrict__ Xb, const u16* __restrict__ W1t,
    const u16* __restrict__ W2t, const float* __restrict__ b1,
    const float* __restrict__ b2, const int* __restrict__ cnt,
    const int* __restrict__ tok, const float* __restrict__ wgt,
    float* __restrict__ out) {
  int e = blockIdx.y;
  int n = cnt[e];
  int m0 = blockIdx.x * BM;
  if (m0 >= n) return;

  __shared__ u16 Xs[64][1032];   // pad 8 -> 4-bank rotation per row, 16B aligned
  __shared__ u16 Hc[64][72];     // pad 8
  __shared__ int tokS[64];
  __shared__ float wgtS[64];

  int tid = threadIdx.x;
  if (tid < 64) {
    int s = m0 + tid;
    if (s < n) { tokS[tid] = tok[e * T + s]; wgtS[tid] = wgt[e * T + s]; }
    else       { tokS[tid] = 0;              wgtS[tid] = 0.f; }
  }
  __syncthreads();

  {  // gather X tile (bf16) into LDS: 8 threads per row, uint4 chunks
    int row = tid >> 3, part = tid & 7;
    const uint4* srcr = reinterpret_cast<const uint4*>(Xb + (size_t)tokS[row] * H);
#pragma unroll
    for (int i = 0; i < 16; ++i) {
      uint4 v = srcr[part + (i << 3)];
      *reinterpret_cast<uint4*>(&Xs[row][(part + (i << 3)) << 3]) = v;
    }
  }
  __syncthreads();

  int wave = tid >> 6, lane = tid & 63;
  int quad = lane >> 4, l16 = lane & 15;
  // phase-1 tile pair for this wave: tiles 2w, 2w+1 share nt
  int tA = wave * 2;
  int mtA = tA & 3, mtB = (tA + 1) & 3, ntP = tA >> 2;

  const size_t eW = (size_t)e * F * H;
  const u16* W1e = W1t + eW;  // [F][H] k-contiguous
  const u16* W2e = W2t + eW;  // [H][F] k-contiguous
  int fbase = blockIdx.z * (F / 2);

  floatx4 acc[4][8];
#pragma unroll
  for (int mt = 0; mt < 4; ++mt)
#pragma unroll
    for (int nt = 0; nt < 8; ++nt) acc[mt][nt] = floatx4{0.f, 0.f, 0.f, 0.f};

  for (int cIdx = 0; cIdx < 32; ++cIdx) {
    int f = fbase + (cIdx << 6);
    // ---- phase 1: Hc[64][64] = gelu(Xs @ W1t[:, f:f+64] + b1) ----
    floatx4 hA = floatx4{0.f, 0.f, 0.f, 0.f};
    floatx4 hB = floatx4{0.f, 0.f, 0.f, 0.f};
    const u16* w1p = W1e + (size_t)(f + ntP * 16 + l16) * H + quad * 8;
    const u16* aArow = &Xs[mtA * 16 + l16][quad * 8];
    const u16* aBrow = &Xs[mtB * 16 + l16][quad * 8];
#pragma unroll 4
    for (int k = 0; k < H; k += 32) {
      short8 bfr = *reinterpret_cast<const short8*>(w1p + k);
      short8 aA = *reinterpret_cast<const short8*>(aArow + k);
      short8 aB = *reinterpret_cast<const short8*>(aBrow + k);
      hA = __builtin_amdgcn_mfma_f32_16x16x32_bf16(aA, bfr, hA, 0, 0, 0);
      hB = __builtin_amdgcn_mfma_f32_16x16x32_bf16(aB, bfr, hB, 0, 0, 0);
    }
    float bia = b1[e * F + f + ntP * 16 + l16];
#pragma unroll
    for (int i = 0; i < 4; ++i) {
      float vA = hA[i] + bia;
      vA = 0.5f * vA * (1.0f + erff(vA * 0.70710678118f));
      Hc[mtA * 16 + quad * 4 + i][ntP * 16 + l16] = f2bf(vA);
      float vB = hB[i] + bia;
      vB = 0.5f * vB * (1.0f + erff(vB * 0.70710678118f));
      Hc[mtB * 16 + quad * 4 + i][ntP * 16 + l16] = f2bf(vB);
    }
    __syncthreads();

    // ---- phase 2: acc += Hc @ W2t[cols, f:f+64] ----
#pragma unroll
    for (int kk = 0; kk < 2; ++kk) {
      short8 afr[4];
#pragma unroll
      for (int mt = 0; mt < 4; ++mt)
        afr[mt] = *reinterpret_cast<const short8*>(&Hc[mt * 16 + l16][kk * 32 + quad * 8]);
#pragma unroll
      for (int nt = 0; nt < 8; ++nt) {
        const u16* w2p = W2e + (size_t)(wave * 128 + nt * 16 + l16) * F + f + kk * 32 + quad * 8;
        short8 bfr = *reinterpret_cast<const short8*>(w2p);
#pragma unroll
        for (int mt = 0; mt < 4; ++mt)
          acc[mt][nt] = __builtin_amdgcn_mfma_f32_16x16x32_bf16(afr[mt], bfr, acc[mt][nt], 0, 0, 0);
      }
    }
    __syncthreads();
  }

  // ---- epilogue: out[tok] += w * (acc + b2) ----
  bool addB2 = (blockIdx.z == 0);
  float b2v[8];
#pragma unroll
  for (int nt = 0; nt < 8; ++nt)
    b2v[nt] = addB2 ? b2[e * H + wave * 128 + nt * 16 + l16] : 0.0f;
#pragma unroll
  for (int mt = 0; mt < 4; ++mt) {
#pragma unroll
    for (int i = 0; i < 4; ++i) {
      int row = mt * 16 + quad * 4 + i;
      if (m0 + row < n) {
        float wv = wgtS[row];
        float* orow = out + (size_t)tokS[row] * H + wave * 128 + l16;
#pragma unroll
        for (int nt = 0; nt < 8; ++nt)
          atomicAdd(orow + nt * 16, (acc[mt][nt][i] + b2v[nt]) * wv);
      }
    }
  }
}

extern "C" void kernel_launch(void* const* d_in, const int* in_sizes, int n_in,
                              void* d_out, int out_size, void* d_ws, size_t ws_size,
                              hipStream_t stream) {
  const float* x  = (const float*)d_in[0];
  const float* Wr = (const float*)d_in[1];
  const float* W1 = (const float*)d_in[2];
  const float* b1 = (const float*)d_in[3];
  const float* W2 = (const float*)d_in[4];
  const float* b2 = (const float*)d_in[5];
  float* out = (float*)d_out;

  char* ws = (char*)d_ws;
  // layout: cnt(32B) | tok(128KB) | wgt(128KB) | Xb(8MB) | W1t(64MB) | W2t(64MB)
  int*  cnt = (int*)(ws + 0);
  int*  tok = (int*)(ws + 256);
  float* wgt = (float*)(ws + 256 + 131072);
  u16*  Xb  = (u16*)(ws + 262400);
  u16*  W1t = (u16*)(ws + 8651008);
  u16*  W2t = (u16*)(ws + 75759872);

  hipMemsetAsync(cnt, 0, 32, stream);
  hipMemsetAsync(out, 0, (size_t)out_size * sizeof(float), stream);

  router_kernel<<<dim3(T / 4), dim3(256), 0, stream>>>(x, Wr, cnt, tok, wgt);
  convert_x_kernel<<<dim3((T * H / 4) / 256), dim3(256), 0, stream>>>(x, Xb);
  transpose_bf16_kernel<<<dim3(F / 32, H / 32, NE), dim3(32, 8), 0, stream>>>(W1, W1t, H, F);
  transpose_bf16_kernel<<<dim3(H / 32, F / 32, NE), dim3(32, 8), 0, stream>>>(W2, W2t, F, H);
  moe_ffn_kernel<<<dim3(T / BM, NE, 2), dim3(512), 0, stream>>>(
      Xb, W1t, W2t, b1, b2, cnt, tok, wgt, out);
}

// Round 2
// 699.533 us; speedup vs baseline: 1.9047x; 1.9047x over previous
//
#include <hip/hip_runtime.h>
#include <hip/hip_bf16.h>

#define H 1024
#define F 4096
#define NE 8
#define T 4096

typedef unsigned short u16;
typedef float floatx4 __attribute__((ext_vector_type(4)));
typedef short short8 __attribute__((ext_vector_type(8)));

__device__ __forceinline__ u16 f2bf(float f) {
  union { float f; unsigned int u; } c; c.f = f;
  unsigned int u = c.u;
  return (u16)((u + 0x7fffu + ((u >> 16) & 1u)) >> 16);
}

// async global->LDS, 16B per lane. LDS dest must be uniform base + lane*16.
__device__ __forceinline__ void load16_lds(const u16* g, u16* l) {
  __builtin_amdgcn_global_load_lds(
      (const __attribute__((address_space(1))) unsigned int*)g,
      (__attribute__((address_space(3))) unsigned int*)l, 16, 0, 0);
}

// ---------------- router: one wave per token, fp64 logits ----------------
__global__ __launch_bounds__(256) void router_kernel(
    const float* __restrict__ x, const float* __restrict__ Wr,
    int* __restrict__ cnt, int* __restrict__ tok, float* __restrict__ wgt) {
  int t = (blockIdx.x * 256 + threadIdx.x) >> 6;
  int lane = threadIdx.x & 63;
  const float* xr = x + (size_t)t * H;
  double p[NE];
#pragma unroll
  for (int e = 0; e < NE; ++e) p[e] = 0.0;
  for (int k = lane; k < H; k += 64) {
    float xv = xr[k];
    const float4* wr4 = reinterpret_cast<const float4*>(Wr + k * NE);
    float4 a = wr4[0], b = wr4[1];
    p[0] += (double)xv * a.x; p[1] += (double)xv * a.y;
    p[2] += (double)xv * a.z; p[3] += (double)xv * a.w;
    p[4] += (double)xv * b.x; p[5] += (double)xv * b.y;
    p[6] += (double)xv * b.z; p[7] += (double)xv * b.w;
  }
#pragma unroll
  for (int e = 0; e < NE; ++e) {
#pragma unroll
    for (int off = 32; off; off >>= 1) p[e] += __shfl_down(p[e], off, 64);
  }
  if (lane == 0) {
    int i0 = 0;
#pragma unroll
    for (int e = 1; e < NE; ++e) if (p[e] > p[i0]) i0 = e;
    int i1 = (i0 == 0) ? 1 : 0;
#pragma unroll
    for (int e = 0; e < NE; ++e) if (e != i0 && p[e] > p[i1]) i1 = e;
    double d = exp(p[i1] - p[i0]);
    float w0 = (float)(1.0 / (1.0 + d));
    float w1 = (float)(d / (1.0 + d));
    int pos0 = atomicAdd(&cnt[i0], 1);
    tok[i0 * T + pos0] = t; wgt[i0 * T + pos0] = w0;
    int pos1 = atomicAdd(&cnt[i1], 1);
    tok[i1 * T + pos1] = t; wgt[i1 * T + pos1] = w1;
  }
}

__global__ void offsets_kernel(const int* __restrict__ cnt, int* __restrict__ off) {
  if (threadIdx.x == 0) {
    int s = 0;
#pragma unroll
    for (int e = 0; e < NE; ++e) { off[e] = s; s += cnt[e]; }
    off[NE] = s;
  }
}

// ---------------- x -> bf16 ----------------
__global__ __launch_bounds__(256) void convert_x_kernel(
    const float* __restrict__ x, u16* __restrict__ xb) {
  int i = blockIdx.x * 256 + threadIdx.x;
  float4 v = reinterpret_cast<const float4*>(x)[i];
  ushort4 o;
  o.x = f2bf(v.x); o.y = f2bf(v.y); o.z = f2bf(v.z); o.w = f2bf(v.w);
  reinterpret_cast<ushort4*>(xb)[i] = o;
}

// ---------------- [E][R][C] f32 -> [E][C][R] bf16, 64x64 tiles ----------------
__global__ __launch_bounds__(256) void transpose_bf16_kernel(
    const float* __restrict__ src, u16* __restrict__ dst, int R, int C) {
  __shared__ u16 tile[64][72];
  int e = blockIdx.z;
  int c0 = blockIdx.x << 6, r0 = blockIdx.y << 6;
  const float* s = src + (size_t)e * R * C;
  u16* d = dst + (size_t)e * R * C;
  int t = threadIdx.x;
  int rl = t >> 4, cl = (t & 15) << 2;
#pragma unroll
  for (int i = 0; i < 4; ++i) {
    float4 v = *reinterpret_cast<const float4*>(&s[(size_t)(r0 + rl + i * 16) * C + c0 + cl]);
    ushort4 o; o.x = f2bf(v.x); o.y = f2bf(v.y); o.z = f2bf(v.z); o.w = f2bf(v.w);
    *reinterpret_cast<ushort4*>(&tile[rl + i * 16][cl]) = o;
  }
  __syncthreads();
  int cl2 = t >> 4, rl2 = (t & 15) << 2;
#pragma unroll
  for (int i = 0; i < 4; ++i) {
    ushort4 o;
    o.x = tile[rl2 + 0][cl2 + i * 16];
    o.y = tile[rl2 + 1][cl2 + i * 16];
    o.z = tile[rl2 + 2][cl2 + i * 16];
    o.w = tile[rl2 + 3][cl2 + i * 16];
    *reinterpret_cast<ushort4*>(&d[(size_t)(c0 + cl2 + i * 16) * R + r0 + rl2]) = o;
  }
}

// ---------------- GEMM1: Hc = gelu(gather(Xb) @ W1t^T + b1) ----------------
// grid: (F/128, 32 m-tiles, NE). 256 thr = 4 waves (2x2 of 64x64).
__global__ __launch_bounds__(256) void gemm1_kernel(
    const u16* __restrict__ Xb, const u16* __restrict__ W1t,
    const float* __restrict__ b1, const int* __restrict__ cnt,
    const int* __restrict__ off, const int* __restrict__ tok,
    u16* __restrict__ Hc) {
  int e = blockIdx.z;
  int n = cnt[e];
  int m0 = blockIdx.y << 7;
  if (m0 >= n) return;
  int n0 = blockIdx.x << 7;
  int rb = off[e];

  __shared__ alignas(16) u16 As[128 * 32];
  __shared__ alignas(16) u16 Bs[128 * 32];
  __shared__ int tokS[128];

  int tid = threadIdx.x;
  if (tid < 128) {
    int s = m0 + tid;
    tokS[tid] = (s < n) ? tok[e * T + s] : 0;
  }
  __syncthreads();

  const u16* W1e = W1t + (size_t)e * F * H;
  // staging pointers: chunk c covers row c>>2, k-span (c&3)*8..+8 (16B)
  const u16* aP0 = Xb + (size_t)tokS[tid >> 2] * H + (tid & 3) * 8;
  const u16* aP1 = Xb + (size_t)tokS[64 + (tid >> 2)] * H + (tid & 3) * 8;
  const u16* bP0 = W1e + (size_t)(n0 + (tid >> 2)) * H + (tid & 3) * 8;
  const u16* bP1 = W1e + (size_t)(n0 + 64 + (tid >> 2)) * H + (tid & 3) * 8;
  u16* aL0 = &As[tid * 8];        u16* aL1 = &As[(tid + 256) * 8];
  u16* bL0 = &Bs[tid * 8];        u16* bL1 = &Bs[(tid + 256) * 8];

  int wv = tid >> 6, lane = tid & 63;
  int wm = wv >> 1, wn = wv & 1;
  int quad = lane >> 4, l16 = lane & 15;

  floatx4 acc[4][4];
#pragma unroll
  for (int mt = 0; mt < 4; ++mt)
#pragma unroll
    for (int nt = 0; nt < 4; ++nt) acc[mt][nt] = floatx4{0.f, 0.f, 0.f, 0.f};

  const u16* aF[4]; const u16* bF[4];
#pragma unroll
  for (int i = 0; i < 4; ++i) {
    aF[i] = &As[(wm * 64 + i * 16 + l16) * 32 + quad * 8];
    bF[i] = &Bs[(wn * 64 + i * 16 + l16) * 32 + quad * 8];
  }

  for (int k0 = 0; k0 < H; k0 += 32) {
    load16_lds(aP0 + k0, aL0);
    load16_lds(aP1 + k0, aL1);
    load16_lds(bP0 + k0, bL0);
    load16_lds(bP1 + k0, bL1);
    __syncthreads();
    short8 av[4], bv[4];
#pragma unroll
    for (int i = 0; i < 4; ++i) {
      av[i] = *reinterpret_cast<const short8*>(aF[i]);
      bv[i] = *reinterpret_cast<const short8*>(bF[i]);
    }
#pragma unroll
    for (int mt = 0; mt < 4; ++mt)
#pragma unroll
      for (int nt = 0; nt < 4; ++nt)
        acc[mt][nt] = __builtin_amdgcn_mfma_f32_16x16x32_bf16(av[mt], bv[nt], acc[mt][nt], 0, 0, 0);
    __syncthreads();
  }

  // epilogue: bias + exact gelu -> bf16 -> Hc[rb + row][col]
  float b1v[4];
#pragma unroll
  for (int nt = 0; nt < 4; ++nt)
    b1v[nt] = b1[e * F + n0 + wn * 64 + nt * 16 + l16];
#pragma unroll
  for (int mt = 0; mt < 4; ++mt) {
#pragma unroll
    for (int i = 0; i < 4; ++i) {
      int row = wm * 64 + mt * 16 + quad * 4 + i;
      int gr = m0 + row;
      if (gr < n) {
        u16* hrow = Hc + (size_t)(rb + gr) * F + n0 + wn * 64 + l16;
#pragma unroll
        for (int nt = 0; nt < 4; ++nt) {
          float v = acc[mt][nt][i] + b1v[nt];
          v = 0.5f * v * (1.0f + erff(v * 0.70710678118f));
          hrow[nt * 16] = f2bf(v);
        }
      }
    }
  }
}

// ---------------- GEMM2: out += w * (Hc @ W2t^T + b2) ----------------
// grid: (H/128, 32 m-tiles, NE). atomic fp32 epilogue into zeroed out.
__global__ __launch_bounds__(256) void gemm2_kernel(
    const u16* __restrict__ Hc, const u16* __restrict__ W2t,
    const float* __restrict__ b2, const int* __restrict__ cnt,
    const int* __restrict__ off, const int* __restrict__ tok,
    const float* __restrict__ wgt, float* __restrict__ out) {
  int e = blockIdx.z;
  int n = cnt[e];
  int m0 = blockIdx.y << 7;
  if (m0 >= n) return;
  int n0 = blockIdx.x << 7;
  int rb = off[e];

  __shared__ alignas(16) u16 As[128 * 32];
  __shared__ alignas(16) u16 Bs[128 * 32];

  int tid = threadIdx.x;
  const u16* W2e = W2t + (size_t)e * F * H;
  const u16* aP0 = Hc + (size_t)(rb + m0 + (tid >> 2)) * F + (tid & 3) * 8;
  const u16* aP1 = Hc + (size_t)(rb + m0 + 64 + (tid >> 2)) * F + (tid & 3) * 8;
  const u16* bP0 = W2e + (size_t)(n0 + (tid >> 2)) * F + (tid & 3) * 8;
  const u16* bP1 = W2e + (size_t)(n0 + 64 + (tid >> 2)) * F + (tid & 3) * 8;
  u16* aL0 = &As[tid * 8];        u16* aL1 = &As[(tid + 256) * 8];
  u16* bL0 = &Bs[tid * 8];        u16* bL1 = &Bs[(tid + 256) * 8];

  int wv = tid >> 6, lane = tid & 63;
  int wm = wv >> 1, wn = wv & 1;
  int quad = lane >> 4, l16 = lane & 15;

  floatx4 acc[4][4];
#pragma unroll
  for (int mt = 0; mt < 4; ++mt)
#pragma unroll
    for (int nt = 0; nt < 4; ++nt) acc[mt][nt] = floatx4{0.f, 0.f, 0.f, 0.f};

  const u16* aF[4]; const u16* bF[4];
#pragma unroll
  for (int i = 0; i < 4; ++i) {
    aF[i] = &As[(wm * 64 + i * 16 + l16) * 32 + quad * 8];
    bF[i] = &Bs[(wn * 64 + i * 16 + l16) * 32 + quad * 8];
  }

  for (int k0 = 0; k0 < F; k0 += 32) {
    load16_lds(aP0 + k0, aL0);
    load16_lds(aP1 + k0, aL1);
    load16_lds(bP0 + k0, bL0);
    load16_lds(bP1 + k0, bL1);
    __syncthreads();
    short8 av[4], bv[4];
#pragma unroll
    for (int i = 0; i < 4; ++i) {
      av[i] = *reinterpret_cast<const short8*>(aF[i]);
      bv[i] = *reinterpret_cast<const short8*>(bF[i]);
    }
#pragma unroll
    for (int mt = 0; mt < 4; ++mt)
#pragma unroll
      for (int nt = 0; nt < 4; ++nt)
        acc[mt][nt] = __builtin_amdgcn_mfma_f32_16x16x32_bf16(av[mt], bv[nt], acc[mt][nt], 0, 0, 0);
    __syncthreads();
  }

  float b2v[4];
#pragma unroll
  for (int nt = 0; nt < 4; ++nt)
    b2v[nt] = b2[e * H + n0 + wn * 64 + nt * 16 + l16];
#pragma unroll
  for (int mt = 0; mt < 4; ++mt) {
#pragma unroll
    for (int i = 0; i < 4; ++i) {
      int row = wm * 64 + mt * 16 + quad * 4 + i;
      int gr = m0 + row;
      if (gr < n) {
        float wv2 = wgt[e * T + gr];
        int tk = tok[e * T + gr];
        float* orow = out + (size_t)tk * H + n0 + wn * 64 + l16;
#pragma unroll
        for (int nt = 0; nt < 4; ++nt)
          atomicAdd(orow + nt * 16, (acc[mt][nt][i] + b2v[nt]) * wv2);
      }
    }
  }
}

extern "C" void kernel_launch(void* const* d_in, const int* in_sizes, int n_in,
                              void* d_out, int out_size, void* d_ws, size_t ws_size,
                              hipStream_t stream) {
  const float* x  = (const float*)d_in[0];
  const float* Wr = (const float*)d_in[1];
  const float* W1 = (const float*)d_in[2];
  const float* b1 = (const float*)d_in[3];
  const float* W2 = (const float*)d_in[4];
  const float* b2 = (const float*)d_in[5];
  float* out = (float*)d_out;

  char* ws = (char*)d_ws;
  // cnt@0 off@256 tok@4096(128K) wgt@135168(128K) Xb@266240(8M)
  // W1t@8654848(64M) W2t@75763712(64M) Hc@142872576(65M+slack) -> ~201MB total
  int*   cnt = (int*)(ws + 0);
  int*   off = (int*)(ws + 256);
  int*   tok = (int*)(ws + 4096);
  float* wgt = (float*)(ws + 135168);
  u16*   Xb  = (u16*)(ws + 266240);
  u16*   W1t = (u16*)(ws + 8654848);
  u16*   W2t = (u16*)(ws + 75763712);
  u16*   Hc  = (u16*)(ws + 142872576);

  hipMemsetAsync(cnt, 0, 64, stream);
  hipMemsetAsync(out, 0, (size_t)out_size * sizeof(float), stream);

  router_kernel<<<dim3(T / 4), dim3(256), 0, stream>>>(x, Wr, cnt, tok, wgt);
  offsets_kernel<<<dim3(1), dim3(64), 0, stream>>>(cnt, off);
  convert_x_kernel<<<dim3((T * H / 4) / 256), dim3(256), 0, stream>>>(x, Xb);
  transpose_bf16_kernel<<<dim3(F / 64, H / 64, NE), dim3(256), 0, stream>>>(W1, W1t, H, F);
  transpose_bf16_kernel<<<dim3(H / 64, F / 64, NE), dim3(256), 0, stream>>>(W2, W2t, F, H);
  gemm1_kernel<<<dim3(F / 128, 32, NE), dim3(256), 0, stream>>>(Xb, W1t, b1, cnt, off, tok, Hc);
  gemm2_kernel<<<dim3(H / 128, 32, NE), dim3(256), 0, stream>>>(Hc, W2t, b2, cnt, off, tok, wgt, out);
}